// Round 11
// baseline (1041.630 us; speedup 1.0000x reference)
//
#include <hip/hip_runtime.h>
#include <hip/hip_fp16.h>
#include <math.h>

#define NN   16384
#define DD   512
#define KNN  16
#define CAND 24          // candidates/row (margin rank16->24 ~6.6e-3 >> 1e-4 err)
#define STRIPW 4096      // fp16 sim strip: 16384 x 4096 x 2B = 128 MB (fits LLC)
#define NSTRIP (NN / STRIPW)

typedef __attribute__((ext_vector_type(8))) short bf16x8;
typedef __attribute__((ext_vector_type(4))) float f32x4;
typedef unsigned int u32;

// async global->LDS, 16B per lane; dest = wave-uniform base + lane*16
__device__ __forceinline__ void load16_lds(const ushort* g, void* l) {
    __builtin_amdgcn_global_load_lds(
        (const __attribute__((address_space(1))) u32*)(const void*)g,
        (__attribute__((address_space(3))) u32*)l, 16, 0, 0);
}

__device__ inline ushort bf16rne(float f) {
    unsigned u = __float_as_uint(f);
    u += 0x7fffu + ((u >> 16) & 1u);
    return (ushort)(u >> 16);
}

// ---- Pass 0 (fused): norms (bit-exact np.linalg.norm replica, R6-verified)
//      + fn = feature/nrm (IEEE-CR div) + bf16 copy.  64 rows/block. --------
__global__ __launch_bounds__(256) void norm_fn_kernel(const float* __restrict__ feat,
                                                      float* __restrict__ nrm,
                                                      float* __restrict__ fn,
                                                      ushort* __restrict__ fnb) {
#pragma clang fp contract(off)
    const int t   = threadIdx.x;
    const int row = blockIdx.x * 64 + (t >> 2);
    const int bid = t & 3;
    const float4* p4 = (const float4*)(feat + (size_t)row * DD + bid * 128);
    float r[4][4];
    #pragma unroll
    for (int m = 0; m < 4; m++) {
        float4 q = p4[m];
        r[m][0] = q.x * q.x; r[m][1] = q.y * q.y;
        r[m][2] = q.z * q.z; r[m][3] = q.w * q.w;
    }
    #pragma unroll
    for (int tt = 1; tt < 8; tt++) {
        #pragma unroll
        for (int m = 0; m < 4; m++) {
            float4 q = p4[tt * 4 + m];
            r[m][0] += q.x * q.x; r[m][1] += q.y * q.y;
            r[m][2] += q.z * q.z; r[m][3] += q.w * q.w;
        }
    }
    float v0 = (r[0][0] + r[1][0]) + (r[2][0] + r[3][0]);
    float v1 = (r[0][1] + r[1][1]) + (r[2][1] + r[3][1]);
    float v2 = (r[0][2] + r[1][2]) + (r[2][2] + r[3][2]);
    float v3 = (r[0][3] + r[1][3]) + (r[2][3] + r[3][3]);
    float B  = (v0 + v1) + (v2 + v3);
    B += __shfl_xor(B, 1, 64);
    B += __shfl_xor(B, 2, 64);
    float nv = sqrtf(B) + 1e-10f;        // identical in all 4 lanes of the row
    __shared__ float snrm[64];
    if (bid == 0) { nrm[row] = nv; snrm[t >> 2] = nv; }
    __syncthreads();
    // fn phase: 64 rows x 128 float4, coalesced
    const int base4 = blockIdx.x * 8192;
    for (int i = t; i < 8192; i += 256) {
        int lrow = i >> 7;
        float n = snrm[lrow];
        float4 v = ((const float4*)feat)[base4 + i];
        float4 o = make_float4(v.x / n, v.y / n, v.z / n, v.w / n);
        ((float4*)fn)[base4 + i] = o;
        ushort4 b = {bf16rne(o.x), bf16rne(o.y), bf16rne(o.z), bf16rne(o.w)};
        ((ushort4*)fnb)[base4 + i] = b;
    }
}

// ---- Pass 1a: bf16 MFMA GEMM -> fp16 sim strip.  128x256 block tile --------
// (m105-verified shape) for 85 FLOP/B staging intensity; 4 waves of 64x128;
// BK=64 async staging with 8-row-segment XOR swizzle (reads 2-way max = free).
__global__ __launch_bounds__(256) void gemm_kernel(const ushort* __restrict__ fnb,
                                                   int stripBase,
                                                   __half* __restrict__ simS) {
    __shared__ ushort As[128 * 64];   // 16 KB
    __shared__ ushort Bs[256 * 64];   // 32 KB
    const int t    = threadIdx.x;
    const int wave = t >> 6, lane = t & 63;
    const int rbase = blockIdx.y * 128;
    const int cbL   = blockIdx.x * 256;
    const int wr = (wave >> 1) * 64, wc = (wave & 1) * 128;
    const int m = lane & 15, quad = lane >> 4;
    const int rseg = lane >> 3;             // row within 8-row segment
    const int cchk = (lane & 7) ^ rseg;     // swizzled global 16B-chunk index
    const int swz  = ((m & 7) << 4);        // reader-side xor key (bytes)

    f32x4 acc[4][8];
    #pragma unroll
    for (int i = 0; i < 4; i++)
        #pragma unroll
        for (int j = 0; j < 8; j++) acc[i][j] = (f32x4){0.f, 0.f, 0.f, 0.f};

    for (int kb = 0; kb < DD; kb += 64) {
        __syncthreads();                    // prev chunk frag reads done
        #pragma unroll
        for (int q = 0; q < 4; q++) {       // A: 16 segs of 8 rows
            int s   = wave * 4 + q;
            int row = s * 8 + rseg;
            load16_lds(fnb + (size_t)(rbase + row) * DD + kb + cchk * 8,
                       (char*)As + s * 1024);
        }
        #pragma unroll
        for (int q = 0; q < 8; q++) {       // B: 32 segs of 8 rows
            int s   = wave * 8 + q;
            int row = s * 8 + rseg;
            load16_lds(fnb + (size_t)(stripBase + cbL + row) * DD + kb + cchk * 8,
                       (char*)Bs + s * 1024);
        }
        __syncthreads();                    // drains vmcnt (compiler-enforced)

        #pragma unroll
        for (int ks = 0; ks < 64; ks += 32) {
            const int off = ((((ks >> 3) + quad) << 4)) ^ swz;
            bf16x8 af[4], bv[8];
            #pragma unroll
            for (int i = 0; i < 4; i++)
                af[i] = *(const bf16x8*)((const char*)As + (wr + i * 16 + m) * 128 + off);
            #pragma unroll
            for (int j = 0; j < 8; j++)
                bv[j] = *(const bf16x8*)((const char*)Bs + (wc + j * 16 + m) * 128 + off);
            #pragma unroll
            for (int i = 0; i < 4; i++)
                #pragma unroll
                for (int j = 0; j < 8; j++)
                    acc[i][j] = __builtin_amdgcn_mfma_f32_16x16x32_bf16(
                        af[i], bv[j], acc[i][j], 0, 0, 0);
        }
    }
    // C/D mapping (m89-verified): col=lane&15, row=(lane>>4)*4+reg
    #pragma unroll
    for (int i = 0; i < 4; i++)
        #pragma unroll
        for (int j = 0; j < 8; j++)
            #pragma unroll
            for (int r = 0; r < 4; r++) {
                int grow = rbase + wr + i * 16 + quad * 4 + r;
                int gcol = cbL + wc + j * 16 + m;
                simS[(size_t)grow * STRIPW + gcol] = __float2half(acc[i][j][r]);
            }
}

// ---- Pass 1b: update per-row top-CAND from an fp16 sim strip (half2) -------
// One wave per row; sorted (v desc, idx asc) list in lanes 0..CAND-1.
__global__ __launch_bounds__(256) void select_kernel(const __half2* __restrict__ simS2,
                                                     int stripBase, int firstStrip,
                                                     float* __restrict__ lval,
                                                     int* __restrict__ lidx) {
    const int lane = threadIdx.x & 63;
    const int row  = blockIdx.x * 4 + (threadIdx.x >> 6);
    float lv; int li;
    if (firstStrip) { lv = -3.4e38f; li = 0x7fffffff; }
    else {
        lv = (lane < CAND) ? lval[(size_t)row * CAND + lane] : -3.4e38f;
        li = (lane < CAND) ? lidx[(size_t)row * CAND + lane] : 0x7fffffff;
    }
    const __half2* sp = simS2 + (size_t)row * (STRIPW / 2);
    for (int it = 0; it < STRIPW / 128; it++) {
        __half2 h = sp[it * 64 + lane];
        float v0 = __low2float(h), v1 = __high2float(h);
        int c0 = stripBase + it * 128 + lane * 2, c1 = c0 + 1;
        float vmin = __shfl(lv, CAND - 1);
        int   imin = __shfl(li, CAND - 1);
        bool a0 = ((v0 > vmin) || (v0 == vmin && c0 < imin)) && (c0 != row);
        bool a1 = ((v1 > vmin) || (v1 == vmin && c1 < imin)) && (c1 != row);
        unsigned long long m0 = __ballot(a0), m1 = __ballot(a1);
        #pragma unroll
        for (int ph = 0; ph < 2; ph++) {
            unsigned long long mask = ph ? m1 : m0;
            float vv = ph ? v1 : v0;
            while (mask) {
                int src = __builtin_ctzll(mask); mask &= mask - 1;
                float bvv = __shfl(vv, src);
                int   bc  = stripBase + it * 128 + src * 2 + ph;
                bool better = (lv > bvv) || (lv == bvv && li < bc);
                unsigned long long bb = __ballot(better) & ((1ull << CAND) - 1);
                int p = __popcll(bb);
                if (p < CAND) {
                    float pv = __shfl_up(lv, 1);
                    int   pi = __shfl_up(li, 1);
                    float nlv = (lane < p) ? lv : (lane == p ? bvv : pv);
                    int   nli = (lane < p) ? li : (lane == p ? bc : pi);
                    if (lane < CAND) { lv = nlv; li = nli; }
                }
            }
        }
    }
    if (lane < CAND) {
        lval[(size_t)row * CAND + lane] = lv;
        lidx[(size_t)row * CAND + lane] = li;
    }
}

// ---- Pass 2: exact fp32-chain rescore, emit top-16.  ILP=2: each thread
// runs two independent ascending-k fmaf chains (rows w and w+8) -------------
__global__ __launch_bounds__(256) void rescore_kernel(const float* __restrict__ fn,
                                                      const int* __restrict__ lidx,
                                                      int* __restrict__ out) {
    __shared__ float sv[16][CAND];
    __shared__ int   si[16][CAND];
    const int w    = threadIdx.x >> 5;        // 32-lane group 0..7
    const int lane = threadIdx.x & 31;
    const int rowA = blockIdx.x * 16 + w;
    const int rowB = rowA + 8;
    const bool valid = lane < CAND;
    const int cA = valid ? lidx[(size_t)rowA * CAND + lane] : 0;
    const int cB = valid ? lidx[(size_t)rowB * CAND + lane] : 0;
    const float* qA = fn + (size_t)rowA * DD;
    const float* pA = fn + (size_t)cA * DD;
    const float* qB = fn + (size_t)rowB * DD;
    const float* pB = fn + (size_t)cB * DD;
    float sA = 0.0f, sB = 0.0f;
    for (int k = 0; k < DD; k += 8) {   // two independent chains, order exact
        float4 qa0 = *(const float4*)(qA + k),     pa0 = *(const float4*)(pA + k);
        float4 qa1 = *(const float4*)(qA + k + 4), pa1 = *(const float4*)(pA + k + 4);
        float4 qb0 = *(const float4*)(qB + k),     pb0 = *(const float4*)(pB + k);
        float4 qb1 = *(const float4*)(qB + k + 4), pb1 = *(const float4*)(pB + k + 4);
        sA = __builtin_fmaf(qa0.x, pa0.x, sA); sB = __builtin_fmaf(qb0.x, pb0.x, sB);
        sA = __builtin_fmaf(qa0.y, pa0.y, sA); sB = __builtin_fmaf(qb0.y, pb0.y, sB);
        sA = __builtin_fmaf(qa0.z, pa0.z, sA); sB = __builtin_fmaf(qb0.z, pb0.z, sB);
        sA = __builtin_fmaf(qa0.w, pa0.w, sA); sB = __builtin_fmaf(qb0.w, pb0.w, sB);
        sA = __builtin_fmaf(qa1.x, pa1.x, sA); sB = __builtin_fmaf(qb1.x, pb1.x, sB);
        sA = __builtin_fmaf(qa1.y, pa1.y, sA); sB = __builtin_fmaf(qb1.y, pb1.y, sB);
        sA = __builtin_fmaf(qa1.z, pa1.z, sA); sB = __builtin_fmaf(qb1.z, pb1.z, sB);
        sA = __builtin_fmaf(qa1.w, pa1.w, sA); sB = __builtin_fmaf(qb1.w, pb1.w, sB);
    }
    if (valid) {
        sv[w][lane] = sA;     si[w][lane] = cA;
        sv[w + 8][lane] = sB; si[w + 8][lane] = cB;
    }
    __syncthreads();
    if (valid) {
        int rankA = 0, rankB = 0;
        #pragma unroll 8
        for (int mm = 0; mm < CAND; mm++) {
            float va = sv[w][mm], vb = sv[w + 8][mm];
            rankA += (va > sA) || (va == sA && si[w][mm] < cA);
            rankB += (vb > sB) || (vb == sB && si[w + 8][mm] < cB);
        }
        if (rankA < KNN) {
            out[(size_t)rowA * KNN + rankA]            = rowA;
            out[(size_t)NN * KNN + rowA * KNN + rankA] = cA;
        }
        if (rankB < KNN) {
            out[(size_t)rowB * KNN + rankB]            = rowB;
            out[(size_t)NN * KNN + rowB * KNN + rankB] = cB;
        }
    }
}

// ---- tiny-ws fallback norm (bit-exact, standalone) -------------------------
__global__ __launch_bounds__(256) void norm_kernel(const float* __restrict__ feat,
                                                   float* __restrict__ nrm) {
#pragma clang fp contract(off)
    const int t   = threadIdx.x;
    const int row = blockIdx.x * 64 + (t >> 2);
    const int bid = t & 3;
    const float4* p4 = (const float4*)(feat + (size_t)row * DD + bid * 128);
    float r[4][4];
    #pragma unroll
    for (int m = 0; m < 4; m++) {
        float4 q = p4[m];
        r[m][0] = q.x * q.x; r[m][1] = q.y * q.y;
        r[m][2] = q.z * q.z; r[m][3] = q.w * q.w;
    }
    #pragma unroll
    for (int tt = 1; tt < 8; tt++) {
        #pragma unroll
        for (int m = 0; m < 4; m++) {
            float4 q = p4[tt * 4 + m];
            r[m][0] += q.x * q.x; r[m][1] += q.y * q.y;
            r[m][2] += q.z * q.z; r[m][3] += q.w * q.w;
        }
    }
    float v0 = (r[0][0] + r[1][0]) + (r[2][0] + r[3][0]);
    float v1 = (r[0][1] + r[1][1]) + (r[2][1] + r[3][1]);
    float v2 = (r[0][2] + r[1][2]) + (r[2][2] + r[3][2]);
    float v3 = (r[0][3] + r[1][3]) + (r[2][3] + r[3][3]);
    float B  = (v0 + v1) + (v2 + v3);
    B += __shfl_xor(B, 1, 64);
    B += __shfl_xor(B, 2, 64);
    if (bid == 0) nrm[row] = sqrtf(B) + 1e-10f;
}

// ================= R6 exact fused kernel (ws fallback; verified) ============
#define MT 64
#define CT 128
#define KT 32
#define SIM_LD 132
template <bool PRE>
__global__ __launch_bounds__(256) void knn_exact_kernel(const float* __restrict__ src,
                                                        const float* __restrict__ nrm,
                                                        int* __restrict__ out) {
    __shared__ union {
        struct { float As[KT][MT]; float Bs[KT][CT]; } stage;
        float sim[MT][SIM_LD];
    } u;
    __shared__ float tval[MT][KNN];
    __shared__ int   tidx[MT][KNN];
    const int t  = threadIdx.x;
    const int r0 = blockIdx.x * MT;
    const int tx = t & 15;
    const int ty = t >> 4;
    for (int i = t; i < MT * KNN; i += 256) {
        ((float*)tval)[i] = -3.4e38f;
        ((int*)tidx)[i]   = 0;
    }
    const int arow = t >> 2, akq = t & 3;
    const int bcol = t >> 1, bkh = t & 1;
    for (int ct = 0; ct < NN / CT; ct++) {
        const int c0 = ct * CT;
        float acc[4][8];
        #pragma unroll
        for (int rr = 0; rr < 4; rr++)
            #pragma unroll
            for (int cc = 0; cc < 8; cc++) acc[rr][cc] = 0.0f;
        for (int kt = 0; kt < DD / KT; kt++) {
            const int kb = kt * KT;
            __syncthreads();
            {
                const float* ap = src + (size_t)(r0 + arow) * DD + kb + akq * 8;
                float4 a0 = *(const float4*)ap;
                float4 a1 = *(const float4*)(ap + 4);
                if (!PRE) {
                    float nA = nrm[r0 + arow];
                    a0.x /= nA; a0.y /= nA; a0.z /= nA; a0.w /= nA;
                    a1.x /= nA; a1.y /= nA; a1.z /= nA; a1.w /= nA;
                }
                int k0 = akq * 8;
                u.stage.As[k0 + 0][arow] = a0.x; u.stage.As[k0 + 1][arow] = a0.y;
                u.stage.As[k0 + 2][arow] = a0.z; u.stage.As[k0 + 3][arow] = a0.w;
                u.stage.As[k0 + 4][arow] = a1.x; u.stage.As[k0 + 5][arow] = a1.y;
                u.stage.As[k0 + 6][arow] = a1.z; u.stage.As[k0 + 7][arow] = a1.w;
            }
            {
                const float* bp = src + (size_t)(c0 + bcol) * DD + kb + bkh * 16;
                float4 b0 = *(const float4*)bp;
                float4 b1 = *(const float4*)(bp + 4);
                float4 b2 = *(const float4*)(bp + 8);
                float4 b3 = *(const float4*)(bp + 12);
                if (!PRE) {
                    float nB = nrm[c0 + bcol];
                    b0.x /= nB; b0.y /= nB; b0.z /= nB; b0.w /= nB;
                    b1.x /= nB; b1.y /= nB; b1.z /= nB; b1.w /= nB;
                    b2.x /= nB; b2.y /= nB; b2.z /= nB; b2.w /= nB;
                    b3.x /= nB; b3.y /= nB; b3.z /= nB; b3.w /= nB;
                }
                int k0 = bkh * 16;
                u.stage.Bs[k0 +  0][bcol] = b0.x; u.stage.Bs[k0 +  1][bcol] = b0.y;
                u.stage.Bs[k0 +  2][bcol] = b0.z; u.stage.Bs[k0 +  3][bcol] = b0.w;
                u.stage.Bs[k0 +  4][bcol] = b1.x; u.stage.Bs[k0 +  5][bcol] = b1.y;
                u.stage.Bs[k0 +  6][bcol] = b1.z; u.stage.Bs[k0 +  7][bcol] = b1.w;
                u.stage.Bs[k0 +  8][bcol] = b2.x; u.stage.Bs[k0 +  9][bcol] = b2.y;
                u.stage.Bs[k0 + 10][bcol] = b2.z; u.stage.Bs[k0 + 11][bcol] = b2.w;
                u.stage.Bs[k0 + 12][bcol] = b3.x; u.stage.Bs[k0 + 13][bcol] = b3.y;
                u.stage.Bs[k0 + 14][bcol] = b3.z; u.stage.Bs[k0 + 15][bcol] = b3.w;
            }
            __syncthreads();
            #pragma unroll
            for (int kk = 0; kk < KT; kk++) {
                float4 av  = *(const float4*)&u.stage.As[kk][ty * 4];
                float4 bv0 = *(const float4*)&u.stage.Bs[kk][tx * 4];
                float4 bv1 = *(const float4*)&u.stage.Bs[kk][64 + tx * 4];
                float ar[4] = {av.x, av.y, av.z, av.w};
                float br[8] = {bv0.x, bv0.y, bv0.z, bv0.w,
                               bv1.x, bv1.y, bv1.z, bv1.w};
                #pragma unroll
                for (int rr = 0; rr < 4; rr++)
                    #pragma unroll
                    for (int cc = 0; cc < 8; cc++)
                        acc[rr][cc] = __builtin_fmaf(ar[rr], br[cc], acc[rr][cc]);
            }
        }
        __syncthreads();
        {
            #pragma unroll
            for (int rr = 0; rr < 4; rr++) {
                *(float4*)&u.sim[ty * 4 + rr][tx * 4] =
                    make_float4(acc[rr][0], acc[rr][1], acc[rr][2], acc[rr][3]);
                *(float4*)&u.sim[ty * 4 + rr][64 + tx * 4] =
                    make_float4(acc[rr][4], acc[rr][5], acc[rr][6], acc[rr][7]);
            }
        }
        __syncthreads();
        if ((t & 3) == 0) {
            const int lr = t >> 2, grow = r0 + lr;
            float vmin = tval[lr][KNN - 1];
            for (int j = 0; j < CT / 4; j++) {
                float4 v4 = *(const float4*)&u.sim[lr][j * 4];
                float vs[4] = {v4.x, v4.y, v4.z, v4.w};
                #pragma unroll
                for (int e = 0; e < 4; e++) {
                    int cc2 = c0 + j * 4 + e;
                    float v = vs[e];
                    if (cc2 == grow) continue;
                    if (v > vmin) {
                        int p = KNN - 1;
                        while (p > 0 && tval[lr][p - 1] < v) {
                            tval[lr][p] = tval[lr][p - 1];
                            tidx[lr][p] = tidx[lr][p - 1];
                            p--;
                        }
                        tval[lr][p] = v;
                        tidx[lr][p] = cc2;
                        vmin = tval[lr][KNN - 1];
                    }
                }
            }
        }
    }
    __syncthreads();
    for (int i = t; i < MT * KNN; i += 256) {
        int lr = i / KNN, j = i % KNN;
        int grow = r0 + lr;
        out[(size_t)grow * KNN + j]            = grow;
        out[(size_t)NN * KNN + grow * KNN + j] = tidx[lr][j];
    }
}

extern "C" void kernel_launch(void* const* d_in, const int* in_sizes, int n_in,
                              void* d_out, int out_size, void* d_ws, size_t ws_size,
                              hipStream_t stream) {
    const float* feat = (const float*)d_in[0];
    int* out = (int*)d_out;
    char* ws = (char*)d_ws;

    const size_t oNrm  = 0;
    const size_t oFn   = 64 * 1024;
    const size_t oFnb  = oFn  + (size_t)NN * DD * 4;        // +32 MB
    const size_t oLv   = oFnb + (size_t)NN * DD * 2;        // +16 MB
    const size_t oLi   = oLv  + (size_t)NN * CAND * 4;      // +1.5 MB
    const size_t oSim  = oLi  + (size_t)NN * CAND * 4;      // +1.5 MB
    const size_t need  = oSim + (size_t)NN * STRIPW * 2;    // +128 MB
    float*  nrm  = (float*)(ws + oNrm);
    float*  fn   = (float*)(ws + oFn);
    ushort* fnb  = (ushort*)(ws + oFnb);
    float*  lval = (float*)(ws + oLv);
    int*    lidx = (int*)(ws + oLi);
    __half* simS = (__half*)(ws + oSim);

    if (ws_size >= need) {
        norm_fn_kernel<<<NN / 64, 256, 0, stream>>>(feat, nrm, fn, fnb);
        for (int s = 0; s < NSTRIP; s++) {
            dim3 ggrid(STRIPW / 256, NN / 128);
            gemm_kernel<<<ggrid, 256, 0, stream>>>(fnb, s * STRIPW, simS);
            select_kernel<<<NN / 4, 256, 0, stream>>>((const __half2*)simS,
                                                      s * STRIPW, s == 0,
                                                      lval, lidx);
        }
        rescore_kernel<<<NN / 16, 256, 0, stream>>>(fn, lidx, out);
    } else if (ws_size >= oLv) {
        norm_fn_kernel<<<NN / 64, 256, 0, stream>>>(feat, nrm, fn, fnb);
        knn_exact_kernel<true><<<NN / MT, 256, 0, stream>>>(fn, nrm, out);
    } else {
        norm_kernel<<<NN / 64, 256, 0, stream>>>(feat, nrm);
        knn_exact_kernel<false><<<NN / MT, 256, 0, stream>>>(feat, nrm, out);
    }
}

// Round 12
// 850.258 us; speedup vs baseline: 1.2251x; 1.2251x over previous
//
#include <hip/hip_runtime.h>
#include <hip/hip_fp16.h>
#include <math.h>

#define NN   16384
#define DD   512
#define KNN  16
#define CAND 20          // candidates/row (rank16->20 margin ~3.3e-3 >> 2.6e-4 err)
#define STRIPW 4096      // fp16 sim strip: 16384 x 4096 x 2B = 128 MB (fits LLC)
#define NSTRIP (NN / STRIPW)

typedef __attribute__((ext_vector_type(8))) short bf16x8;
typedef __attribute__((ext_vector_type(4))) float f32x4;
typedef unsigned int u32;

// async global->LDS, 16B per lane; dest = wave-uniform base + lane*16
__device__ __forceinline__ void load16_lds(const ushort* g, void* l) {
    __builtin_amdgcn_global_load_lds(
        (const __attribute__((address_space(1))) u32*)(const void*)g,
        (__attribute__((address_space(3))) u32*)l, 16, 0, 0);
}

__device__ inline ushort bf16rne(float f) {
    unsigned u = __float_as_uint(f);
    u += 0x7fffu + ((u >> 16) & 1u);
    return (ushort)(u >> 16);
}

// ---- Pass 0 (fused): norms (bit-exact np.linalg.norm replica, R6-verified)
//      + fn = feature/nrm (IEEE-CR div) + bf16 copy.  64 rows/block. --------
__global__ __launch_bounds__(256) void norm_fn_kernel(const float* __restrict__ feat,
                                                      float* __restrict__ nrm,
                                                      float* __restrict__ fn,
                                                      ushort* __restrict__ fnb) {
#pragma clang fp contract(off)
    const int t   = threadIdx.x;
    const int row = blockIdx.x * 64 + (t >> 2);
    const int bid = t & 3;
    const float4* p4 = (const float4*)(feat + (size_t)row * DD + bid * 128);
    float r[4][4];
    #pragma unroll
    for (int m = 0; m < 4; m++) {
        float4 q = p4[m];
        r[m][0] = q.x * q.x; r[m][1] = q.y * q.y;
        r[m][2] = q.z * q.z; r[m][3] = q.w * q.w;
    }
    #pragma unroll
    for (int tt = 1; tt < 8; tt++) {
        #pragma unroll
        for (int m = 0; m < 4; m++) {
            float4 q = p4[tt * 4 + m];
            r[m][0] += q.x * q.x; r[m][1] += q.y * q.y;
            r[m][2] += q.z * q.z; r[m][3] += q.w * q.w;
        }
    }
    float v0 = (r[0][0] + r[1][0]) + (r[2][0] + r[3][0]);
    float v1 = (r[0][1] + r[1][1]) + (r[2][1] + r[3][1]);
    float v2 = (r[0][2] + r[1][2]) + (r[2][2] + r[3][2]);
    float v3 = (r[0][3] + r[1][3]) + (r[2][3] + r[3][3]);
    float B  = (v0 + v1) + (v2 + v3);
    B += __shfl_xor(B, 1, 64);
    B += __shfl_xor(B, 2, 64);
    float nv = sqrtf(B) + 1e-10f;        // identical in all 4 lanes of the row
    __shared__ float snrm[64];
    if (bid == 0) { nrm[row] = nv; snrm[t >> 2] = nv; }
    __syncthreads();
    const int base4 = blockIdx.x * 8192;
    for (int i = t; i < 8192; i += 256) {
        int lrow = i >> 7;
        float n = snrm[lrow];
        float4 v = ((const float4*)feat)[base4 + i];
        float4 o = make_float4(v.x / n, v.y / n, v.z / n, v.w / n);
        ((float4*)fn)[base4 + i] = o;
        ushort4 b = {bf16rne(o.x), bf16rne(o.y), bf16rne(o.z), bf16rne(o.w)};
        ((ushort4*)fnb)[base4 + i] = b;
    }
}

// ---- Pass 1a: bf16 MFMA GEMM -> fp16 sim strip (R10-verified 128x128) ------
// 256 thr = 4 waves (2x2 of 64x64), BK=64 async staging with 8-row-segment
// XOR swizzle (frag reads 2-way max = free).
__global__ __launch_bounds__(256) void gemm_kernel(const ushort* __restrict__ fnb,
                                                   int stripBase,
                                                   __half* __restrict__ simS) {
    __shared__ ushort As[128 * 64];   // 16 KB
    __shared__ ushort Bs[128 * 64];   // 16 KB
    const int t    = threadIdx.x;
    const int wave = t >> 6, lane = t & 63;
    const int rbase = blockIdx.y * 128;
    const int cbL   = blockIdx.x * 128;
    const int wr = (wave >> 1) * 64, wc = (wave & 1) * 64;
    const int m = lane & 15, quad = lane >> 4;
    const int rseg = lane >> 3;
    const int cchk = (lane & 7) ^ rseg;
    const int swz  = ((m & 7) << 4);

    f32x4 acc[4][4];
    #pragma unroll
    for (int i = 0; i < 4; i++)
        #pragma unroll
        for (int j = 0; j < 4; j++) acc[i][j] = (f32x4){0.f, 0.f, 0.f, 0.f};

    for (int kb = 0; kb < DD; kb += 64) {
        __syncthreads();
        #pragma unroll
        for (int q = 0; q < 4; q++) {
            int s   = wave * 4 + q;
            int row = s * 8 + rseg;
            const ushort* ga = fnb + (size_t)(rbase + row) * DD + kb + cchk * 8;
            const ushort* gb = fnb + (size_t)(stripBase + cbL + row) * DD + kb + cchk * 8;
            load16_lds(ga, (char*)As + s * 1024);
            load16_lds(gb, (char*)Bs + s * 1024);
        }
        __syncthreads();

        #pragma unroll
        for (int ks = 0; ks < 64; ks += 32) {
            const int off = ((((ks >> 3) + quad) << 4)) ^ swz;
            bf16x8 af[4], bv[4];
            #pragma unroll
            for (int i = 0; i < 4; i++)
                af[i] = *(const bf16x8*)((const char*)As + (wr + i * 16 + m) * 128 + off);
            #pragma unroll
            for (int j = 0; j < 4; j++)
                bv[j] = *(const bf16x8*)((const char*)Bs + (wc + j * 16 + m) * 128 + off);
            #pragma unroll
            for (int i = 0; i < 4; i++)
                #pragma unroll
                for (int j = 0; j < 4; j++)
                    acc[i][j] = __builtin_amdgcn_mfma_f32_16x16x32_bf16(
                        af[i], bv[j], acc[i][j], 0, 0, 0);
        }
    }
    // C/D mapping (m89-verified): col=lane&15, row=(lane>>4)*4+reg
    #pragma unroll
    for (int i = 0; i < 4; i++)
        #pragma unroll
        for (int j = 0; j < 4; j++)
            #pragma unroll
            for (int r = 0; r < 4; r++) {
                int grow = rbase + wr + i * 16 + quad * 4 + r;
                int gcol = cbL + wc + j * 16 + m;
                simS[(size_t)grow * STRIPW + gcol] = __float2half(acc[i][j][r]);
            }
}

// ---- Pass 1b: update per-row top-CAND from an fp16 sim strip (half2) -------
// One wave per row; sorted (v desc, idx asc) list in lanes 0..CAND-1.
__global__ __launch_bounds__(256) void select_kernel(const __half2* __restrict__ simS2,
                                                     int stripBase, int firstStrip,
                                                     float* __restrict__ lval,
                                                     int* __restrict__ lidx) {
    const int lane = threadIdx.x & 63;
    const int row  = blockIdx.x * 4 + (threadIdx.x >> 6);
    float lv; int li;
    if (firstStrip) { lv = -3.4e38f; li = 0x7fffffff; }
    else {
        lv = (lane < CAND) ? lval[(size_t)row * CAND + lane] : -3.4e38f;
        li = (lane < CAND) ? lidx[(size_t)row * CAND + lane] : 0x7fffffff;
    }
    const __half2* sp = simS2 + (size_t)row * (STRIPW / 2);
    for (int it = 0; it < STRIPW / 128; it++) {
        __half2 h = sp[it * 64 + lane];
        float v0 = __low2float(h), v1 = __high2float(h);
        int c0 = stripBase + it * 128 + lane * 2, c1 = c0 + 1;
        float vmin = __shfl(lv, CAND - 1);
        int   imin = __shfl(li, CAND - 1);
        bool a0 = ((v0 > vmin) || (v0 == vmin && c0 < imin)) && (c0 != row);
        bool a1 = ((v1 > vmin) || (v1 == vmin && c1 < imin)) && (c1 != row);
        unsigned long long m0 = __ballot(a0), m1 = __ballot(a1);
        #pragma unroll
        for (int ph = 0; ph < 2; ph++) {
            unsigned long long mask = ph ? m1 : m0;
            float vv = ph ? v1 : v0;
            while (mask) {
                int src = __builtin_ctzll(mask); mask &= mask - 1;
                float bvv = __shfl(vv, src);
                int   bc  = stripBase + it * 128 + src * 2 + ph;
                bool better = (lv > bvv) || (lv == bvv && li < bc);
                unsigned long long bb = __ballot(better) & ((1ull << CAND) - 1);
                int p = __popcll(bb);
                if (p < CAND) {
                    float pv = __shfl_up(lv, 1);
                    int   pi = __shfl_up(li, 1);
                    float nlv = (lane < p) ? lv : (lane == p ? bvv : pv);
                    int   nli = (lane < p) ? li : (lane == p ? bc : pi);
                    if (lane < CAND) { lv = nlv; li = nli; }
                }
            }
        }
    }
    if (lane < CAND) {
        lval[(size_t)row * CAND + lane] = lv;
        lidx[(size_t)row * CAND + lane] = li;
    }
}

// ---- Pass 2: exact fp32-chain rescore, emit top-16 (R10-verified shape) ----
// Bitwise-replicates the reference sim: single ascending-k fmaf chain on fn.
__global__ __launch_bounds__(256) void rescore_kernel(const float* __restrict__ fn,
                                                      const int* __restrict__ lidx,
                                                      int* __restrict__ out) {
    __shared__ float sv[8][CAND];
    __shared__ int   si[8][CAND];
    const int w    = threadIdx.x >> 5;        // 32-lane group 0..7
    const int lane = threadIdx.x & 31;
    const int row  = blockIdx.x * 8 + w;
    const bool valid = lane < CAND;
    const int c = valid ? lidx[(size_t)row * CAND + lane] : 0;
    const float* q = fn + (size_t)row * DD;
    const float* p = fn + (size_t)c * DD;
    float s = 0.0f;
    for (int k = 0; k < DD; k += 16) {   // wide loads for MLP; chain order exact
        float4 q0 = *(const float4*)(q + k),      p0 = *(const float4*)(p + k);
        float4 q1 = *(const float4*)(q + k + 4),  p1 = *(const float4*)(p + k + 4);
        float4 q2 = *(const float4*)(q + k + 8),  p2 = *(const float4*)(p + k + 8);
        float4 q3 = *(const float4*)(q + k + 12), p3 = *(const float4*)(p + k + 12);
        s = __builtin_fmaf(q0.x, p0.x, s); s = __builtin_fmaf(q0.y, p0.y, s);
        s = __builtin_fmaf(q0.z, p0.z, s); s = __builtin_fmaf(q0.w, p0.w, s);
        s = __builtin_fmaf(q1.x, p1.x, s); s = __builtin_fmaf(q1.y, p1.y, s);
        s = __builtin_fmaf(q1.z, p1.z, s); s = __builtin_fmaf(q1.w, p1.w, s);
        s = __builtin_fmaf(q2.x, p2.x, s); s = __builtin_fmaf(q2.y, p2.y, s);
        s = __builtin_fmaf(q2.z, p2.z, s); s = __builtin_fmaf(q2.w, p2.w, s);
        s = __builtin_fmaf(q3.x, p3.x, s); s = __builtin_fmaf(q3.y, p3.y, s);
        s = __builtin_fmaf(q3.z, p3.z, s); s = __builtin_fmaf(q3.w, p3.w, s);
    }
    if (valid) { sv[w][lane] = s; si[w][lane] = c; }
    __syncthreads();
    if (valid) {
        int rank = 0;
        #pragma unroll 4
        for (int mm = 0; mm < CAND; mm++) {
            float vm = sv[w][mm];
            rank += (vm > s) || (vm == s && si[w][mm] < c);
        }
        if (rank < KNN) {
            out[(size_t)row * KNN + rank]            = row;
            out[(size_t)NN * KNN + row * KNN + rank] = c;
        }
    }
}

// ---- tiny-ws fallback norm (bit-exact, standalone) -------------------------
__global__ __launch_bounds__(256) void norm_kernel(const float* __restrict__ feat,
                                                   float* __restrict__ nrm) {
#pragma clang fp contract(off)
    const int t   = threadIdx.x;
    const int row = blockIdx.x * 64 + (t >> 2);
    const int bid = t & 3;
    const float4* p4 = (const float4*)(feat + (size_t)row * DD + bid * 128);
    float r[4][4];
    #pragma unroll
    for (int m = 0; m < 4; m++) {
        float4 q = p4[m];
        r[m][0] = q.x * q.x; r[m][1] = q.y * q.y;
        r[m][2] = q.z * q.z; r[m][3] = q.w * q.w;
    }
    #pragma unroll
    for (int tt = 1; tt < 8; tt++) {
        #pragma unroll
        for (int m = 0; m < 4; m++) {
            float4 q = p4[tt * 4 + m];
            r[m][0] += q.x * q.x; r[m][1] += q.y * q.y;
            r[m][2] += q.z * q.z; r[m][3] += q.w * q.w;
        }
    }
    float v0 = (r[0][0] + r[1][0]) + (r[2][0] + r[3][0]);
    float v1 = (r[0][1] + r[1][1]) + (r[2][1] + r[3][1]);
    float v2 = (r[0][2] + r[1][2]) + (r[2][2] + r[3][2]);
    float v3 = (r[0][3] + r[1][3]) + (r[2][3] + r[3][3]);
    float B  = (v0 + v1) + (v2 + v3);
    B += __shfl_xor(B, 1, 64);
    B += __shfl_xor(B, 2, 64);
    if (bid == 0) nrm[row] = sqrtf(B) + 1e-10f;
}

// ================= R6 exact fused kernel (ws fallback; verified) ============
#define MT 64
#define CT 128
#define KT 32
#define SIM_LD 132
template <bool PRE>
__global__ __launch_bounds__(256) void knn_exact_kernel(const float* __restrict__ src,
                                                        const float* __restrict__ nrm,
                                                        int* __restrict__ out) {
    __shared__ union {
        struct { float As[KT][MT]; float Bs[KT][CT]; } stage;
        float sim[MT][SIM_LD];
    } u;
    __shared__ float tval[MT][KNN];
    __shared__ int   tidx[MT][KNN];
    const int t  = threadIdx.x;
    const int r0 = blockIdx.x * MT;
    const int tx = t & 15;
    const int ty = t >> 4;
    for (int i = t; i < MT * KNN; i += 256) {
        ((float*)tval)[i] = -3.4e38f;
        ((int*)tidx)[i]   = 0;
    }
    const int arow = t >> 2, akq = t & 3;
    const int bcol = t >> 1, bkh = t & 1;
    for (int ct = 0; ct < NN / CT; ct++) {
        const int c0 = ct * CT;
        float acc[4][8];
        #pragma unroll
        for (int rr = 0; rr < 4; rr++)
            #pragma unroll
            for (int cc = 0; cc < 8; cc++) acc[rr][cc] = 0.0f;
        for (int kt = 0; kt < DD / KT; kt++) {
            const int kb = kt * KT;
            __syncthreads();
            {
                const float* ap = src + (size_t)(r0 + arow) * DD + kb + akq * 8;
                float4 a0 = *(const float4*)ap;
                float4 a1 = *(const float4*)(ap + 4);
                if (!PRE) {
                    float nA = nrm[r0 + arow];
                    a0.x /= nA; a0.y /= nA; a0.z /= nA; a0.w /= nA;
                    a1.x /= nA; a1.y /= nA; a1.z /= nA; a1.w /= nA;
                }
                int k0 = akq * 8;
                u.stage.As[k0 + 0][arow] = a0.x; u.stage.As[k0 + 1][arow] = a0.y;
                u.stage.As[k0 + 2][arow] = a0.z; u.stage.As[k0 + 3][arow] = a0.w;
                u.stage.As[k0 + 4][arow] = a1.x; u.stage.As[k0 + 5][arow] = a1.y;
                u.stage.As[k0 + 6][arow] = a1.z; u.stage.As[k0 + 7][arow] = a1.w;
            }
            {
                const float* bp = src + (size_t)(c0 + bcol) * DD + kb + bkh * 16;
                float4 b0 = *(const float4*)bp;
                float4 b1 = *(const float4*)(bp + 4);
                float4 b2 = *(const float4*)(bp + 8);
                float4 b3 = *(const float4*)(bp + 12);
                if (!PRE) {
                    float nB = nrm[c0 + bcol];
                    b0.x /= nB; b0.y /= nB; b0.z /= nB; b0.w /= nB;
                    b1.x /= nB; b1.y /= nB; b1.z /= nB; b1.w /= nB;
                    b2.x /= nB; b2.y /= nB; b2.z /= nB; b2.w /= nB;
                    b3.x /= nB; b3.y /= nB; b3.z /= nB; b3.w /= nB;
                }
                int k0 = bkh * 16;
                u.stage.Bs[k0 +  0][bcol] = b0.x; u.stage.Bs[k0 +  1][bcol] = b0.y;
                u.stage.Bs[k0 +  2][bcol] = b0.z; u.stage.Bs[k0 +  3][bcol] = b0.w;
                u.stage.Bs[k0 +  4][bcol] = b1.x; u.stage.Bs[k0 +  5][bcol] = b1.y;
                u.stage.Bs[k0 +  6][bcol] = b1.z; u.stage.Bs[k0 +  7][bcol] = b1.w;
                u.stage.Bs[k0 +  8][bcol] = b2.x; u.stage.Bs[k0 +  9][bcol] = b2.y;
                u.stage.Bs[k0 + 10][bcol] = b2.z; u.stage.Bs[k0 + 11][bcol] = b2.w;
                u.stage.Bs[k0 + 12][bcol] = b3.x; u.stage.Bs[k0 + 13][bcol] = b3.y;
                u.stage.Bs[k0 + 14][bcol] = b3.z; u.stage.Bs[k0 + 15][bcol] = b3.w;
            }
            __syncthreads();
            #pragma unroll
            for (int kk = 0; kk < KT; kk++) {
                float4 av  = *(const float4*)&u.stage.As[kk][ty * 4];
                float4 bv0 = *(const float4*)&u.stage.Bs[kk][tx * 4];
                float4 bv1 = *(const float4*)&u.stage.Bs[kk][64 + tx * 4];
                float ar[4] = {av.x, av.y, av.z, av.w};
                float br[8] = {bv0.x, bv0.y, bv0.z, bv0.w,
                               bv1.x, bv1.y, bv1.z, bv1.w};
                #pragma unroll
                for (int rr = 0; rr < 4; rr++)
                    #pragma unroll
                    for (int cc = 0; cc < 8; cc++)
                        acc[rr][cc] = __builtin_fmaf(ar[rr], br[cc], acc[rr][cc]);
            }
        }
        __syncthreads();
        {
            #pragma unroll
            for (int rr = 0; rr < 4; rr++) {
                *(float4*)&u.sim[ty * 4 + rr][tx * 4] =
                    make_float4(acc[rr][0], acc[rr][1], acc[rr][2], acc[rr][3]);
                *(float4*)&u.sim[ty * 4 + rr][64 + tx * 4] =
                    make_float4(acc[rr][4], acc[rr][5], acc[rr][6], acc[rr][7]);
            }
        }
        __syncthreads();
        if ((t & 3) == 0) {
            const int lr = t >> 2, grow = r0 + lr;
            float vmin = tval[lr][KNN - 1];
            for (int j = 0; j < CT / 4; j++) {
                float4 v4 = *(const float4*)&u.sim[lr][j * 4];
                float vs[4] = {v4.x, v4.y, v4.z, v4.w};
                #pragma unroll
                for (int e = 0; e < 4; e++) {
                    int cc2 = c0 + j * 4 + e;
                    float v = vs[e];
                    if (cc2 == grow) continue;
                    if (v > vmin) {
                        int p = KNN - 1;
                        while (p > 0 && tval[lr][p - 1] < v) {
                            tval[lr][p] = tval[lr][p - 1];
                            tidx[lr][p] = tidx[lr][p - 1];
                            p--;
                        }
                        tval[lr][p] = v;
                        tidx[lr][p] = cc2;
                        vmin = tval[lr][KNN - 1];
                    }
                }
            }
        }
    }
    __syncthreads();
    for (int i = t; i < MT * KNN; i += 256) {
        int lr = i / KNN, j = i % KNN;
        int grow = r0 + lr;
        out[(size_t)grow * KNN + j]            = grow;
        out[(size_t)NN * KNN + grow * KNN + j] = tidx[lr][j];
    }
}

extern "C" void kernel_launch(void* const* d_in, const int* in_sizes, int n_in,
                              void* d_out, int out_size, void* d_ws, size_t ws_size,
                              hipStream_t stream) {
    const float* feat = (const float*)d_in[0];
    int* out = (int*)d_out;
    char* ws = (char*)d_ws;

    const size_t oNrm  = 0;
    const size_t oFn   = 64 * 1024;
    const size_t oFnb  = oFn  + (size_t)NN * DD * 4;        // +32 MB
    const size_t oLv   = oFnb + (size_t)NN * DD * 2;        // +16 MB
    const size_t oLi   = oLv  + (size_t)NN * CAND * 4;      // +1.25 MB
    const size_t oSim  = oLi  + (size_t)NN * CAND * 4;      // +1.25 MB
    const size_t need  = oSim + (size_t)NN * STRIPW * 2;    // +128 MB
    float*  nrm  = (float*)(ws + oNrm);
    float*  fn   = (float*)(ws + oFn);
    ushort* fnb  = (ushort*)(ws + oFnb);
    float*  lval = (float*)(ws + oLv);
    int*    lidx = (int*)(ws + oLi);
    __half* simS = (__half*)(ws + oSim);

    if (ws_size >= need) {
        norm_fn_kernel<<<NN / 64, 256, 0, stream>>>(feat, nrm, fn, fnb);
        for (int s = 0; s < NSTRIP; s++) {
            dim3 ggrid(STRIPW / 128, NN / 128);
            gemm_kernel<<<ggrid, 256, 0, stream>>>(fnb, s * STRIPW, simS);
            select_kernel<<<NN / 4, 256, 0, stream>>>((const __half2*)simS,
                                                      s * STRIPW, s == 0,
                                                      lval, lidx);
        }
        rescore_kernel<<<NN / 8, 256, 0, stream>>>(fn, lidx, out);
    } else if (ws_size >= oLv) {
        norm_fn_kernel<<<NN / 64, 256, 0, stream>>>(feat, nrm, fn, fnb);
        knn_exact_kernel<true><<<NN / MT, 256, 0, stream>>>(fn, nrm, out);
    } else {
        norm_kernel<<<NN / 64, 256, 0, stream>>>(feat, nrm);
        knn_exact_kernel<false><<<NN / MT, 256, 0, stream>>>(feat, nrm, out);
    }
}